// Round 6
// baseline (30.906 us; speedup 1.0000x reference)
//
#include <hip/hip_runtime.h>
#include <hip/hip_bf16.h>
#include <hip/hip_fp16.h>
#include <math.h>

#define BB 32
#define NN 2048
#define BLK 256
#define QPW 2                       // 32-query groups per wave
#define ITILE 256                   // 4 waves * 64 queries
#define NTIL (NN / ITILE)           // 8
#define NBLK (2 * BB * NTIL)        // 512 blocks = 2/CU
#define JT (NN / 32)                // 64 j-tiles of 32 targets
#define PF 4                        // prefetch group size (j-tiles)
#define NGRP (JT / PF)              // 16 groups

typedef _Float16 f16x8 __attribute__((ext_vector_type(8)));
typedef float f32x16 __attribute__((ext_vector_type(16)));

__device__ __forceinline__ unsigned pk2h(float a, float b) {
  union { _Float16 h[2]; unsigned u; } v;
  v.h[0] = (_Float16)a; v.h[1] = (_Float16)b;
  return v.u;
}

// 17-input min: 16 MFMA lanes + running min, 8 v_min3-shaped folds.
__device__ __forceinline__ float min17(const f32x16& d, float mn) {
  float g0 = fminf(fminf(d[0], d[1]), d[2]);
  float g1 = fminf(fminf(d[3], d[4]), d[5]);
  float g2 = fminf(fminf(d[6], d[7]), d[8]);
  float g3 = fminf(fminf(d[9], d[10]), d[11]);
  float g4 = fminf(fminf(d[12], d[13]), d[14]);
  float h0 = fminf(fminf(g0, g1), g2);
  float h1 = fminf(fminf(g3, g4), d[15]);
  return fminf(fminf(h0, h1), mn);
}

// Fused chamfer + BCE, single kernel. Block (dir, b, it): stages all 2048
// targets of (dir,b) as packed A-frags (y0,y1,y2,|y|^2/2 duplicated in both
// k-halves -> D = |y|^2 - 2 x.y). Each wave owns 64 queries (2 B-frags of
// -x,1). Ping-pong register prefetch (PF=4 j-tiles) hides ds_read latency
// under the previous group's 8 MFMAs + min trees. Epilogue: d2 = max(x^2 +
// min, 0) + BCE (dir==0), block sum, one atomicAdd into out (pre-zeroed by
// a 4-byte memset node).
__global__ __launch_bounds__(BLK) void cham_fused(
    const float* __restrict__ est, const float* __restrict__ gt,
    const float* __restrict__ lest, const float* __restrict__ lab,
    float* __restrict__ out) {
  int id = blockIdx.x;
  int it = id % NTIL; id /= NTIL;
  int b = id % BB;
  int dir = id / BB;

  const float* X = dir ? gt : est;   // queries
  const float* Y = dir ? est : gt;   // targets

  __shared__ uint4 sy[JT][32];       // 32 KB packed A-fragments

  const float* yb = Y + (size_t)b * NN * 3;
#pragma unroll
  for (int jj = 0; jj < NN / BLK; ++jj) {
    int j = jj * BLK + threadIdx.x;
    float y0 = yb[3 * j], y1 = yb[3 * j + 1], y2 = yb[3 * j + 2];
    float h = 0.5f * (y0 * y0 + y1 * y1 + y2 * y2);
    uint4 u;
    u.x = pk2h(y0, y1);
    u.y = pk2h(y2, h);
    u.z = 0u; u.w = 0u;
    sy[j >> 5][j & 31] = u;
  }
  __syncthreads();

  int lane = threadIdx.x & 63;
  int w = threadIdx.x >> 6;
  int l31 = lane & 31;
  int q0 = it * ITILE + w * 64 + l31;
  int q1 = q0 + 32;

  const float* xp0 = X + ((size_t)b * NN + q0) * 3;
  const float* xp1 = X + ((size_t)b * NN + q1) * 3;
  float x00 = xp0[0], x01 = xp0[1], x02 = xp0[2];
  float x10 = xp1[0], x11 = xp1[1], x12 = xp1[2];
  uint4 u0, u1;
  u0.x = pk2h(-x00, -x01); u0.y = pk2h(-x02, 1.0f); u0.z = 0u; u0.w = 0u;
  u1.x = pk2h(-x10, -x11); u1.y = pk2h(-x12, 1.0f); u1.z = 0u; u1.w = 0u;
  f16x8 bf0 = __builtin_bit_cast(f16x8, u0);
  f16x8 bf1 = __builtin_bit_cast(f16x8, u1);

  const f32x16 zz = {0.f, 0.f, 0.f, 0.f, 0.f, 0.f, 0.f, 0.f,
                     0.f, 0.f, 0.f, 0.f, 0.f, 0.f, 0.f, 0.f};
  float mn0 = 3.4e38f, mn1 = 3.4e38f;

  f16x8 A0[PF], A1[PF];
#pragma unroll
  for (int p = 0; p < PF; ++p)
    A0[p] = __builtin_bit_cast(f16x8, sy[p][l31]);

  for (int g = 0; g < NGRP; g += 2) {
    // prefetch group g+1 while computing group g
#pragma unroll
    for (int p = 0; p < PF; ++p)
      A1[p] = __builtin_bit_cast(f16x8, sy[(g + 1) * PF + p][l31]);
#pragma unroll
    for (int p = 0; p < PF; ++p) {
      f32x16 d0 = __builtin_amdgcn_mfma_f32_32x32x16_f16(A0[p], bf0, zz, 0, 0, 0);
      f32x16 d1 = __builtin_amdgcn_mfma_f32_32x32x16_f16(A0[p], bf1, zz, 0, 0, 0);
      mn0 = min17(d0, mn0);
      mn1 = min17(d1, mn1);
    }
    // prefetch group g+2 while computing group g+1
    if (g + 2 < NGRP) {
#pragma unroll
      for (int p = 0; p < PF; ++p)
        A0[p] = __builtin_bit_cast(f16x8, sy[(g + 2) * PF + p][l31]);
    }
#pragma unroll
    for (int p = 0; p < PF; ++p) {
      f32x16 d0 = __builtin_amdgcn_mfma_f32_32x32x16_f16(A1[p], bf0, zz, 0, 0, 0);
      f32x16 d1 = __builtin_amdgcn_mfma_f32_32x32x16_f16(A1[p], bf1, zz, 0, 0, 0);
      mn0 = min17(d0, mn0);
      mn1 = min17(d1, mn1);
    }
  }

  // merge row halves 0-15 / 16-31 (lanes l and l+32 hold complementary rows)
  mn0 = fminf(mn0, __shfl_xor(mn0, 32, 64));
  mn1 = fminf(mn1, __shfl_xor(mn1, 32, 64));

  float val = 0.0f;
  if (lane < 32) {
    float x2a = fmaf(x00, x00, fmaf(x01, x01, x02 * x02));
    float x2b = fmaf(x10, x10, fmaf(x11, x11, x12 * x12));
    val = fmaxf(x2a + mn0, 0.0f) + fmaxf(x2b + mn1, 0.0f);
    if (!dir) {  // fuse BCE for (b, q0) and (b, q1)
      float z0 = lest[(size_t)b * NN + q0], t0 = lab[(size_t)b * NN + q0];
      float z1 = lest[(size_t)b * NN + q1], t1 = lab[(size_t)b * NN + q1];
      val += fmaxf(z0, 0.0f) - z0 * t0 + log1pf(expf(-fabsf(z0)));
      val += fmaxf(z1, 0.0f) - z1 * t1 + log1pf(expf(-fabsf(z1)));
    }
  }

  for (int off = 32; off > 0; off >>= 1) val += __shfl_down(val, off);
  __shared__ float wsum[BLK / 64];
  if (lane == 0) wsum[w] = val;
  __syncthreads();
  if (threadIdx.x == 0) {
    float s = wsum[0] + wsum[1] + wsum[2] + wsum[3];
    atomicAdd(out, s * (1.0f / ((float)BB * (float)NN)));
  }
}

extern "C" void kernel_launch(void* const* d_in, const int* in_sizes, int n_in,
                              void* d_out, int out_size, void* d_ws, size_t ws_size,
                              hipStream_t stream) {
  const float* est = (const float*)d_in[0];
  const float* gt = (const float*)d_in[1];
  const float* lest = (const float*)d_in[2];
  const float* lab = (const float*)d_in[3];
  float* out = (float*)d_out;

  hipMemsetAsync(out, 0, sizeof(float), stream);
  cham_fused<<<dim3(NBLK), dim3(BLK), 0, stream>>>(est, gt, lest, lab, out);
}

// Round 7
// 21.118 us; speedup vs baseline: 1.4635x; 1.4635x over previous
//
#include <hip/hip_runtime.h>
#include <hip/hip_bf16.h>
#include <hip/hip_fp16.h>
#include <math.h>

#define BB 32
#define NN 2048
#define BLK 256
#define NQG 8                    // query groups (of 32) per block
#define QB (NQG * 32)            // 256 queries per block
#define NCH (NN / QB)            // 8 query chunks
#define NBLK (2 * BB * NCH)      // 512 blocks = 2/CU
#define TPW 16                   // j-tiles (of 32 targets) per wave, in regs

typedef _Float16 f16x8 __attribute__((ext_vector_type(8)));
typedef float f32x16 __attribute__((ext_vector_type(16)));

__device__ __forceinline__ unsigned pk2h(float a, float b) {
  union { _Float16 h[2]; unsigned u; } v;
  v.h[0] = (_Float16)a; v.h[1] = (_Float16)b;
  return v.u;
}

__device__ __forceinline__ f16x8 mkfrag(unsigned a, unsigned b) {
  union { unsigned u[4]; f16x8 f; } v;
  v.u[0] = a; v.u[1] = b; v.u[2] = 0u; v.u[3] = 0u;
  return v.f;
}

// 17-input min: 16 MFMA regs + running min; folds to v_min3 shapes.
__device__ __forceinline__ float min17(const f32x16& d, float mn) {
  float g0 = fminf(fminf(d[0], d[1]), d[2]);
  float g1 = fminf(fminf(d[3], d[4]), d[5]);
  float g2 = fminf(fminf(d[6], d[7]), d[8]);
  float g3 = fminf(fminf(d[9], d[10]), d[11]);
  float g4 = fminf(fminf(d[12], d[13]), d[14]);
  float h0 = fminf(fminf(g0, g1), g2);
  float h1 = fminf(fminf(g3, g4), d[15]);
  return fminf(fminf(h0, h1), mn);
}

// Register-resident chamfer. Block (dir, b, qc): 256 queries vs all 2048
// targets. Wave w holds 16 A-frags (tiles w, w+4, ..., w+60) in VGPRs
// (y0,y1,y2,|y|^2/2 packed f16, zero-padded; both k-halves identical ->
// D = |y|^2 - 2 x.y, validated bit-exact in R4/R5). Inner loop: 8 query
// groups; per group one 8B LDS read -> B-frag (-x0,-x1,-x2,1) -> 16 MFMAs
// -> min trees (4 chains). Per-wave mins to LDS, one sync, cross-wave fold,
// + x^2, + BCE (dir==0), block sum -> bsum. No atomics, no memset.
__global__ __launch_bounds__(BLK) void cham_fused(
    const float* __restrict__ est, const float* __restrict__ gt,
    const float* __restrict__ lest, const float* __restrict__ lab,
    float* __restrict__ bsum) {
  int id = blockIdx.x;
  int qc = id % NCH; id /= NCH;
  int b = id % BB;
  int dir = id / BB;

  const float* X = dir ? gt : est;   // queries
  const float* Y = dir ? est : gt;   // targets

  __shared__ unsigned long long sbq[QB];   // 2 KB packed B-frags
  __shared__ float partial[4][NQG][32];    // 4 KB per-wave mins

  int tid = threadIdx.x;
  int lane = tid & 63, w = tid >> 6, l31 = lane & 31;
  int qbase = qc * QB;

  // stage this block's 256 queries (thread tid <-> query qbase+tid)
  const float* xq = X + ((size_t)b * NN + qbase + tid) * 3;
  float x0 = xq[0], x1 = xq[1], x2 = xq[2];
  {
    union { unsigned u[2]; unsigned long long ull; } pb;
    pb.u[0] = pk2h(-x0, -x1);
    pb.u[1] = pk2h(-x2, 1.0f);
    sbq[tid] = pb.ull;
  }

  // load A-frags into registers (once, L2-hot: 64 blocks share each (dir,b))
  f16x8 A[TPW];
#pragma unroll
  for (int k = 0; k < TPW; ++k) {
    int j = (w + 4 * k) * 32 + l31;
    const float* yp = Y + ((size_t)b * NN + j) * 3;
    float y0 = yp[0], y1 = yp[1], y2 = yp[2];
    float h = 0.5f * (y0 * y0 + y1 * y1 + y2 * y2);
    A[k] = mkfrag(pk2h(y0, y1), pk2h(y2, h));
  }
  __syncthreads();

  const f32x16 zz = {0.f, 0.f, 0.f, 0.f, 0.f, 0.f, 0.f, 0.f,
                     0.f, 0.f, 0.f, 0.f, 0.f, 0.f, 0.f, 0.f};

#pragma unroll 2
  for (int n = 0; n < NQG; ++n) {
    union { unsigned long long ull; unsigned u[2]; } qb;
    qb.ull = sbq[n * 32 + l31];
    f16x8 bf = mkfrag(qb.u[0], qb.u[1]);
    // 4 independent min chains over 16 MFMAs
    float m0 = 3.4e38f, m1 = 3.4e38f, m2 = 3.4e38f, m3 = 3.4e38f;
#pragma unroll
    for (int t = 0; t < TPW; t += 4) {
      f32x16 d0 = __builtin_amdgcn_mfma_f32_32x32x16_f16(A[t + 0], bf, zz, 0, 0, 0);
      f32x16 d1 = __builtin_amdgcn_mfma_f32_32x32x16_f16(A[t + 1], bf, zz, 0, 0, 0);
      f32x16 d2 = __builtin_amdgcn_mfma_f32_32x32x16_f16(A[t + 2], bf, zz, 0, 0, 0);
      f32x16 d3 = __builtin_amdgcn_mfma_f32_32x32x16_f16(A[t + 3], bf, zz, 0, 0, 0);
      m0 = min17(d0, m0);
      m1 = min17(d1, m1);
      m2 = min17(d2, m2);
      m3 = min17(d3, m3);
    }
    float m = fminf(fminf(m0, m1), fminf(m2, m3));
    m = fminf(m, __shfl_xor(m, 32, 64));  // merge row halves
    if (lane < 32) partial[w][n][l31] = m;
  }
  __syncthreads();

  // epilogue: thread tid <-> query qbase+tid; n = tid>>5, col = tid&31
  int n = tid >> 5, col = tid & 31;
  float m = fminf(fminf(partial[0][n][col], partial[1][n][col]),
                  fminf(partial[2][n][col], partial[3][n][col]));
  float x2n = fmaf(x0, x0, fmaf(x1, x1, x2 * x2));
  float val = fmaxf(x2n + m, 0.0f);
  if (!dir) {  // fuse BCE for (b, qbase+tid)
    float z = lest[(size_t)b * NN + qbase + tid];
    float t = lab[(size_t)b * NN + qbase + tid];
    val += fmaxf(z, 0.0f) - z * t + log1pf(expf(-fabsf(z)));
  }

  for (int off = 32; off > 0; off >>= 1) val += __shfl_down(val, off);
  __shared__ float wsum[BLK / 64];
  if (lane == 0) wsum[w] = val;
  __syncthreads();
  if (tid == 0)
    bsum[blockIdx.x] = wsum[0] + wsum[1] + wsum[2] + wsum[3];
}

// Final: sum 512 block partials, scale, store scalar. Deterministic.
__global__ __launch_bounds__(BLK) void sum_kernel(
    const float* __restrict__ bsum, float* __restrict__ out) {
  float val = bsum[threadIdx.x] + bsum[threadIdx.x + BLK];
  for (int off = 32; off > 0; off >>= 1) val += __shfl_down(val, off);
  __shared__ float wsum[BLK / 64];
  int lane = threadIdx.x & 63;
  int wid = threadIdx.x >> 6;
  if (lane == 0) wsum[wid] = val;
  __syncthreads();
  if (threadIdx.x == 0) {
    float s = 0.0f;
#pragma unroll
    for (int wv = 0; wv < BLK / 64; ++wv) s += wsum[wv];
    out[0] = s * (1.0f / ((float)BB * (float)NN));
  }
}

// Fallback (proven-correct R1 kernel) if ws is too small.
__global__ __launch_bounds__(BLK) void chamfer_bce_kernel(
    const float* __restrict__ est, const float* __restrict__ gt,
    const float* __restrict__ lest, const float* __restrict__ lab,
    float* __restrict__ out) {
  int bid = blockIdx.x;
  int dir = (bid >= BB * (NN / BLK)) ? 1 : 0;
  int id = dir ? (bid - BB * (NN / BLK)) : bid;
  int b = id / (NN / BLK);
  int tile = id % (NN / BLK);
  const float* X = dir ? gt : est;
  const float* Y = dir ? est : gt;
  __shared__ float4 sy[NN];
  const float* yb = Y + (size_t)b * NN * 3;
  for (int j = threadIdx.x; j < NN; j += BLK)
    sy[j] = make_float4(yb[3 * j], yb[3 * j + 1], yb[3 * j + 2], 0.0f);
  __syncthreads();
  int i = tile * BLK + threadIdx.x;
  const float* xb = X + (size_t)b * NN * 3 + (size_t)3 * i;
  float ex = xb[0], ey = xb[1], ez = xb[2];
  float m0 = 3.4e38f, m1 = 3.4e38f, m2 = 3.4e38f, m3 = 3.4e38f;
#pragma unroll 4
  for (int j = 0; j < NN; j += 4) {
    float4 p0 = sy[j], p1 = sy[j + 1], p2 = sy[j + 2], p3 = sy[j + 3];
    { float dx = ex - p0.x, dy = ey - p0.y, dz = ez - p0.z;
      m0 = fminf(m0, fmaf(dx, dx, fmaf(dy, dy, dz * dz))); }
    { float dx = ex - p1.x, dy = ey - p1.y, dz = ez - p1.z;
      m1 = fminf(m1, fmaf(dx, dx, fmaf(dy, dy, dz * dz))); }
    { float dx = ex - p2.x, dy = ey - p2.y, dz = ez - p2.z;
      m2 = fminf(m2, fmaf(dx, dx, fmaf(dy, dy, dz * dz))); }
    { float dx = ex - p3.x, dy = ey - p3.y, dz = ez - p3.z;
      m3 = fminf(m3, fmaf(dx, dx, fmaf(dy, dy, dz * dz))); }
  }
  float val = fminf(fminf(m0, m1), fminf(m2, m3));
  if (!dir) {
    float z = lest[(size_t)b * NN + i];
    float t = lab[(size_t)b * NN + i];
    val += fmaxf(z, 0.0f) - z * t + log1pf(expf(-fabsf(z)));
  }
  for (int off = 32; off > 0; off >>= 1) val += __shfl_down(val, off);
  __shared__ float wsum[BLK / 64];
  int lane = threadIdx.x & 63;
  int wid = threadIdx.x >> 6;
  if (lane == 0) wsum[wid] = val;
  __syncthreads();
  if (threadIdx.x == 0) {
    float s = 0.0f;
#pragma unroll
    for (int w = 0; w < BLK / 64; ++w) s += wsum[w];
    atomicAdd(out, s * (1.0f / ((float)BB * (float)NN)));
  }
}

extern "C" void kernel_launch(void* const* d_in, const int* in_sizes, int n_in,
                              void* d_out, int out_size, void* d_ws, size_t ws_size,
                              hipStream_t stream) {
  const float* est = (const float*)d_in[0];
  const float* gt = (const float*)d_in[1];
  const float* lest = (const float*)d_in[2];
  const float* lab = (const float*)d_in[3];
  float* out = (float*)d_out;

  const size_t need = (size_t)NBLK * sizeof(float);  // 2 KB
  if (ws_size >= need) {
    float* bsum = (float*)d_ws;
    cham_fused<<<dim3(NBLK), dim3(BLK), 0, stream>>>(est, gt, lest, lab, bsum);
    sum_kernel<<<dim3(1), dim3(BLK), 0, stream>>>(bsum, out);
  } else {
    hipMemsetAsync(out, 0, sizeof(float), stream);
    chamfer_bce_kernel<<<dim3(2 * BB * (NN / BLK)), dim3(BLK), 0, stream>>>(
        est, gt, lest, lab, out);
  }
}